// Round 12
// baseline (659.129 us; speedup 1.0000x reference)
//
#include <hip/hip_runtime.h>
#include <hip/hip_bf16.h>
#include <stdint.h>

// ---------------- problem constants ----------------
#define ROWS   2048        // B*T
#define DIN    512
#define DEMB   768
#define VSIZE  50257
#define NPAD   50432       // 394 * 128
#define NTILES 394
#define MTILES 16
#define GRID   (MTILES * NTILES)   // 6304 = 8 x 788
#define CAP    1024
#define THRESH 0.089f      // fp8 sims: rank-32 ~0.1163, 20-sigma margin (sigma~1.4e-3)
#define BETAC  10.0f
#define EPSC   1e-8f
#define KSTEPS 6           // 768 / 128
#define RANKN  72          // fp8-approx window exact-reranked in fp32
#define GEMM_BLOCKS 384    // 32 x 12
#define PREP_BLOCKS 2048

typedef __attribute__((ext_vector_type(8))) int   i32x8;
typedef __attribute__((ext_vector_type(4))) int   i32x4;
typedef __attribute__((ext_vector_type(4))) float f32x4;

// float -> OCP e4m3fn, RNE; FTZ below 2^-6 (negligible for unit-variance data)
__device__ __forceinline__ uint32_t f2e4(float f) {
    uint32_t u = __float_as_uint(f);
    uint32_t s = (u >> 24) & 0x80u;
    uint32_t e = (u >> 23) & 0xFFu;
    uint32_t m = u & 0x7FFFFFu;
    if (e < 121u) return s;                       // |x| < ~2^-6 -> 0
    uint32_t t = m + 0x7FFFFu + ((m >> 20) & 1u);
    uint32_t m3 = t >> 20;                        // 0..8
    uint32_t X = e - 120u;                        // e4m3 biased exp pre-round
    if (m3 == 8u) { m3 = 0u; ++X; }
    if (X > 15u || (X == 15u && m3 == 7u)) return s | 0x7Eu;   // clamp 448
    return s | (X << 3) | m3;
}

// ---------------- kernel A+B fused: {emb->fp8 + norms} || {h = x @ proj^T} ----
__global__ __launch_bounds__(256) void prep_fused(const float* __restrict__ X,
                                                  const float* __restrict__ P,
                                                  const float* __restrict__ emb,
                                                  float* __restrict__ H,
                                                  uint8_t* __restrict__ e8,
                                                  float* __restrict__ inve,
                                                  float* __restrict__ enorm) {
    __shared__ float As[64][33];
    __shared__ float Bs[64][33];
    int bid = blockIdx.x;
    int tid = threadIdx.x;

    if (bid < GEMM_BLOCKS) {
        // fp32 exact NT GEMM: h[2048,768] = X[2048,512] @ P[768,512]^T
        int bm = bid & 31;
        int bn = bid >> 5;
        int tx = tid & 15, ty = tid >> 4;
        int lr = tid >> 3;
        int lc = (tid & 7) * 4;
        float acc[4][4] = {};
        for (int k0 = 0; k0 < DIN; k0 += 32) {
            float4 a0 = *(const float4*)(X + (size_t)(bm * 64 + lr) * DIN + k0 + lc);
            float4 a1 = *(const float4*)(X + (size_t)(bm * 64 + lr + 32) * DIN + k0 + lc);
            float4 b0 = *(const float4*)(P + (size_t)(bn * 64 + lr) * DIN + k0 + lc);
            float4 b1 = *(const float4*)(P + (size_t)(bn * 64 + lr + 32) * DIN + k0 + lc);
            __syncthreads();
            As[lr][lc] = a0.x; As[lr][lc + 1] = a0.y; As[lr][lc + 2] = a0.z; As[lr][lc + 3] = a0.w;
            As[lr + 32][lc] = a1.x; As[lr + 32][lc + 1] = a1.y; As[lr + 32][lc + 2] = a1.z; As[lr + 32][lc + 3] = a1.w;
            Bs[lr][lc] = b0.x; Bs[lr][lc + 1] = b0.y; Bs[lr][lc + 2] = b0.z; Bs[lr][lc + 3] = b0.w;
            Bs[lr + 32][lc] = b1.x; Bs[lr + 32][lc + 1] = b1.y; Bs[lr + 32][lc + 2] = b1.z; Bs[lr + 32][lc + 3] = b1.w;
            __syncthreads();
#pragma unroll
            for (int k = 0; k < 32; ++k) {
                float a[4], b[4];
#pragma unroll
                for (int i = 0; i < 4; ++i) a[i] = As[ty * 4 + i][k];
#pragma unroll
                for (int j = 0; j < 4; ++j) b[j] = Bs[tx * 4 + j][k];
#pragma unroll
                for (int i = 0; i < 4; ++i)
#pragma unroll
                    for (int j = 0; j < 4; ++j) acc[i][j] += a[i] * b[j];
            }
        }
#pragma unroll
        for (int i = 0; i < 4; ++i)
#pragma unroll
            for (int j = 0; j < 4; ++j)
                H[(size_t)(bm * 64 + ty * 4 + i) * DEMB + bn * 64 + tx * 4 + j] = acc[i][j];
        return;
    }

    // embeddings: one wave per row, grid-stride; fp8 out + exact fp32 norms
    int lane = tid & 63;
    int wid = (bid - GEMM_BLOCKS) * 4 + (tid >> 6);
    for (int v = wid; v < NPAD; v += PREP_BLOCKS * 4) {
        uint32_t* dst = (uint32_t*)(e8 + (size_t)v * DEMB + lane * 4);
        if (v >= VSIZE) {
            dst[0] = 0u; dst[64] = 0u; dst[128] = 0u;   // +256B, +512B in bytes
            if (lane == 0) { inve[v] = 0.f; enorm[v] = 1.f; }
            continue;
        }
        const float* src = emb + (size_t)v * DEMB + lane * 4;
        float4 x0 = *(const float4*)(src);
        float4 x1 = *(const float4*)(src + 256);
        float4 x2 = *(const float4*)(src + 512);
        dst[0]   = f2e4(x0.x) | (f2e4(x0.y) << 8) | (f2e4(x0.z) << 16) | (f2e4(x0.w) << 24);
        dst[64]  = f2e4(x1.x) | (f2e4(x1.y) << 8) | (f2e4(x1.z) << 16) | (f2e4(x1.w) << 24);
        dst[128] = f2e4(x2.x) | (f2e4(x2.y) << 8) | (f2e4(x2.z) << 16) | (f2e4(x2.w) << 24);
        float s = x0.x*x0.x + x0.y*x0.y + x0.z*x0.z + x0.w*x0.w
                + x1.x*x1.x + x1.y*x1.y + x1.z*x1.z + x1.w*x1.w
                + x2.x*x2.x + x2.y*x2.y + x2.z*x2.z + x2.w*x2.w;
        for (int off = 32; off; off >>= 1) s += __shfl_down(s, off);
        if (lane == 0) {
            float n = sqrtf(s);
            enorm[v] = n;
            inve[v]  = 1.f / n;
        }
    }
}

// ---------------- kernel C: h_norm, 1/h_norm, h -> fp8 ----------------
__global__ void prep_h(const float* __restrict__ H, uint8_t* __restrict__ h8,
                       float* __restrict__ hnorm, float* __restrict__ invh) {
    int r = blockIdx.x;          // 2048
    int t = threadIdx.x;         // 192
    float4 xv = *(const float4*)(H + (size_t)r * DEMB + t * 4);
    *(uint32_t*)(h8 + (size_t)r * DEMB + t * 4) =
        f2e4(xv.x) | (f2e4(xv.y) << 8) | (f2e4(xv.z) << 16) | (f2e4(xv.w) << 24);
    float s = xv.x * xv.x + xv.y * xv.y + xv.z * xv.z + xv.w * xv.w;
    for (int off = 32; off; off >>= 1) s += __shfl_down(s, off);
    __shared__ float wsum[3];
    int lane = t & 63, w = t >> 6;
    if (lane == 0) wsum[w] = s;
    __syncthreads();
    if (t == 0) {
        float n = sqrtf(wsum[0] + wsum[1] + wsum[2]);
        hnorm[r] = n;
        invh[r]  = 1.f / n;
    }
}

// ---------------- kernel D: MX-fp8 (unit-scale) MFMA sims + filter ----------
// R3-proven dbuf skeleton at fp8 K=128: tile 128x128, 512 thr / 8 waves
// (2Mx4N, per-wave 64x32, acc 4x2), BK=128B rows, 6 K-steps, LDS 2x32KB ->
// 2 blocks/CU = 16 waves/CU. Stage t+1 before compute t, vmcnt(4), raw
// s_barrier pair. Slot-XOR swizzle (slot ^= row&7) via pre-swizzled global
// source (rule #21): 2-way-max bank alias (free). mfma_scale_*_f8f6f4 with
// unit scales (0x7F = 1.0) = plain fp8 GEMM at 2x bf16 rate.
#define AS1 __attribute__((address_space(1)))
#define AS3 __attribute__((address_space(3)))
#define STG(gp, lp) __builtin_amdgcn_global_load_lds((const AS1 void*)(gp), (AS3 void*)(lp), 16, 0, 0)

__global__ __launch_bounds__(512, 2) void sim_filter(const uint8_t* __restrict__ A8,
                                                     const uint8_t* __restrict__ B8,
                                                     const float* __restrict__ invh,
                                                     const float* __restrict__ inve,
                                                     int* __restrict__ cnt,
                                                     uint2* __restrict__ cand) {
    __shared__ char lds[65536];      // 2 buf x (A 16KB + B 16KB)
    int bid = blockIdx.x;
    int lb = (bid & 7) * (GRID / 8) + (bid >> 3);   // bijective XCD chunking
    int mt = lb & 15;
    int nt = lb >> 4;
    int m0 = mt * 128, n0 = nt * 128;
    int tid = threadIdx.x, lane = tid & 63, w = tid >> 6;
    int wm = w >> 2, wn = w & 3;
    int rr = lane & 15, hi = lane >> 4;

    // ---- stage sources: chunk = 64 rows x 128B; thread t -> row t>>3, slot t&7
    int r0 = tid >> 3;
    int sg = ((tid & 7) ^ (r0 & 7)) * 16;           // pre-swizzled source byte col
    const uint8_t* sA0 = A8 + (size_t)(m0 + r0) * DEMB + sg;
    const uint8_t* sA1 = A8 + (size_t)(m0 + 64 + r0) * DEMB + sg;
    const uint8_t* sB0 = B8 + (size_t)(n0 + r0) * DEMB + sg;
    const uint8_t* sB1 = B8 + (size_t)(n0 + 64 + r0) * DEMB + sg;
    int wofs = w * 1024;             // wave-uniform dest base within a chunk

    // ---- LDS read byte-offsets (K-invariant): LDS[row][slot]=glob[row][slot^(row&7)]
    int offA0[4], offA1[4], offB0[2], offB1[2];
#pragma unroll
    for (int f = 0; f < 4; ++f) {
        int row = wm * 64 + f * 16 + rr;
        int sx = row & 7;
        offA0[f] = row * 128 + ((2 * hi) ^ sx) * 16;
        offA1[f] = row * 128 + ((2 * hi + 1) ^ sx) * 16;
    }
#pragma unroll
    for (int f = 0; f < 2; ++f) {
        int row = wn * 32 + f * 16 + rr;
        int sx = row & 7;
        offB0[f] = 16384 + row * 128 + ((2 * hi) ^ sx) * 16;
        offB1[f] = 16384 + row * 128 + ((2 * hi + 1) ^ sx) * 16;
    }

    f32x4 acc[4][2];
#pragma unroll
    for (int i = 0; i < 4; ++i)
#pragma unroll
        for (int j = 0; j < 2; ++j) acc[i][j] = (f32x4)(0.f);

#define STAGE(DB)                                                   \
    do {                                                            \
        STG(sA0, (DB) + wofs);                                      \
        STG(sA1, (DB) + 8192 + wofs);                               \
        STG(sB0, (DB) + 16384 + wofs);                              \
        STG(sB1, (DB) + 24576 + wofs);                              \
        sA0 += 128; sA1 += 128; sB0 += 128; sB1 += 128;             \
    } while (0)

    STAGE(lds);                       // prologue: step 0 -> buf 0

    for (int t = 0; t < KSTEPS; ++t) {
        if (t < KSTEPS - 1) {
            char* db = lds + (((t + 1) & 1) << 15);
            STAGE(db);
            asm volatile("s_waitcnt vmcnt(4)" ::: "memory");   // step t landed
        } else {
            asm volatile("s_waitcnt vmcnt(0)" ::: "memory");
        }
        __builtin_amdgcn_s_barrier();        // all waves: buf[t&1] ready
        __builtin_amdgcn_sched_barrier(0);

        const char* cb = lds + ((t & 1) << 15);
        i32x8 a[4], b[2];
#pragma unroll
        for (int f = 0; f < 4; ++f) {
            i32x4 lo = *(const i32x4*)(cb + offA0[f]);
            i32x4 hv = *(const i32x4*)(cb + offA1[f]);
            a[f][0] = lo[0]; a[f][1] = lo[1]; a[f][2] = lo[2]; a[f][3] = lo[3];
            a[f][4] = hv[0]; a[f][5] = hv[1]; a[f][6] = hv[2]; a[f][7] = hv[3];
        }
#pragma unroll
        for (int f = 0; f < 2; ++f) {
            i32x4 lo = *(const i32x4*)(cb + offB0[f]);
            i32x4 hv = *(const i32x4*)(cb + offB1[f]);
            b[f][0] = lo[0]; b[f][1] = lo[1]; b[f][2] = lo[2]; b[f][3] = lo[3];
            b[f][4] = hv[0]; b[f][5] = hv[1]; b[f][6] = hv[2]; b[f][7] = hv[3];
        }
        __builtin_amdgcn_s_setprio(1);
#pragma unroll
        for (int mi = 0; mi < 4; ++mi)
#pragma unroll
            for (int nj = 0; nj < 2; ++nj)
                acc[mi][nj] = __builtin_amdgcn_mfma_scale_f32_16x16x128_f8f6f4(
                    a[mi], b[nj], acc[mi][nj], 0, 0, 0, 0x7F7F7F7Fu, 0, 0x7F7F7F7Fu);
        __builtin_amdgcn_s_setprio(0);

        asm volatile("s_waitcnt lgkmcnt(0)" ::: "memory");
        __builtin_amdgcn_sched_barrier(0);
        __builtin_amdgcn_s_barrier();        // buf[t&1] reusable next iteration
        __builtin_amdgcn_sched_barrier(0);
    }
#undef STAGE

    // epilogue: C/D layout (shape-determined): col=lane&15, row=(lane>>4)*4+reg
    int rbase = hi * 4;
#pragma unroll
    for (int mi = 0; mi < 4; ++mi) {
        int mrow0 = m0 + wm * 64 + mi * 16 + rbase;
#pragma unroll
        for (int nj = 0; nj < 2; ++nj) {
            int ncol = n0 + wn * 32 + nj * 16 + rr;
            float ie = inve[ncol];   // 0 on pad rows -> filtered
#pragma unroll
            for (int r = 0; r < 4; ++r) {
                int m = mrow0 + r;
                float sim = acc[mi][nj][r] * invh[m] * ie;
                if (sim > THRESH) {
                    int pos = atomicAdd(&cnt[m], 1);
                    if (pos < CAP) {
                        uint2 pk;
                        pk.x = __float_as_uint(sim);
                        pk.y = (uint32_t)ncol;
                        cand[(size_t)m * CAP + pos] = pk;
                    }
                }
            }
        }
    }
}

// ---------------- kernel E: full exact fp32 rerank of fp8 top-72 ------------
// fp8 window: true-top-32 inside approx-top-72 with ~6-sigma margin. All 72
// get exact fp32 dots (np formula); selection, weights, and gather all exact
// fp32 -> output matches np to reduction-order noise.
__global__ __launch_bounds__(512) void finalize(const float* __restrict__ H,
                                                const float* __restrict__ emb,
                                                const float* __restrict__ hnorm,
                                                const float* __restrict__ enorm,
                                                const int* __restrict__ cnt,
                                                const uint2* __restrict__ cand,
                                                float* __restrict__ out) {
    int row = blockIdx.x, tid = threadIdx.x;
    __shared__ float cval[CAP];
    __shared__ int   cidx[CAP];
    __shared__ float sval[RANKN];
    __shared__ int   sidx[RANKN];
    __shared__ float exv[RANKN];
    __shared__ float selv[32];
    __shared__ int   seli[32];
    __shared__ float wts[32];

    int n = cnt[row]; if (n > CAP) n = CAP;
    for (int c = tid; c < n; c += 512) {
        uint2 p = cand[(size_t)row * CAP + c];
        cval[c] = __uint_as_float(p.x);
        cidx[c] = (int)p.y;
    }
    if (tid < RANKN) { sval[tid] = -1e30f; sidx[tid] = -1; }
    __syncthreads();

    // approx top-RANKN by rank counting (order-independent -> deterministic)
    for (int c = tid; c < n; c += 512) {
        float v = cval[c]; int id = cidx[c];
        int rank = 0;
        for (int j = 0; j < n; ++j) {
            float vj = cval[j];
            rank += (vj > v) || (vj == v && cidx[j] < id);
        }
        if (rank < RANKN) { sval[rank] = v; sidx[rank] = id; }
    }
    __syncthreads();

    // exact fp32 dots for all RANKN: np formula dot/(h_norm*e_norm+eps)
    int lane = tid & 63, w = tid >> 6;       // 8 waves x 9 reps
    const float* hrow = H + (size_t)row * DEMB;
    float hreg[12];
#pragma unroll
    for (int q = 0; q < 12; ++q) hreg[q] = hrow[lane + 64 * q];
    float hn = hnorm[row];
#pragma unroll
    for (int rep = 0; rep < RANKN / 8; ++rep) {
        int s = w * (RANKN / 8) + rep;
        int id = sidx[s];            // wave-uniform
        float sum = 0.f;
        if (id >= 0) {
            const float* er = emb + (size_t)id * DEMB;
#pragma unroll
            for (int q = 0; q < 12; ++q) sum += hreg[q] * er[lane + 64 * q];
            for (int off = 32; off; off >>= 1) sum += __shfl_down(sum, off);
        }
        if (lane == 0) exv[s] = (id >= 0) ? sum / (hn * enorm[id] + EPSC) : -1e30f;
    }
    if (tid < 32) { selv[tid] = -1e30f; seli[tid] = -1; }
    __syncthreads();

    // exact top-32 among the 72, ties by lower embedding index (jax semantics)
    if (tid < RANKN) {
        float v = exv[tid];
        int id = sidx[tid];
        int keyme = (id >= 0) ? id : 1000000 + tid;
        int rank = 0;
        for (int j = 0; j < RANKN; ++j) {
            float vj = exv[j];
            int kj = (sidx[j] >= 0) ? sidx[j] : 1000000 + j;
            rank += (vj > v) || (vj == v && kj < keyme);
        }
        if (rank < 32) { selv[rank] = v; seli[rank] = id; }
    }
    __syncthreads();

    if (tid == 0) {
        float mx = selv[0];
        float s = 0.f;
        for (int r = 0; r < 32; ++r) {
            float e = (seli[r] >= 0) ? expf(BETAC * (selv[r] - mx)) : 0.f;
            wts[r] = e; s += e;
        }
        float inv = 1.f / s;
        for (int r = 0; r < 32; ++r) wts[r] *= inv;
    }
    __syncthreads();

    // output: weighted sum over fp32 emb rows (rows are L2-hot from rerank)
    for (int col = tid; col < DEMB; col += 512) {
        float acc = 0.f;
        for (int r = 0; r < 32; ++r) {
            int id = seli[r];
            if (id >= 0) acc += wts[r] * emb[(size_t)id * DEMB + col];
        }
        out[(size_t)row * DEMB + col] = acc;
    }
}

// ---------------- launch ----------------
extern "C" void kernel_launch(void* const* d_in, const int* in_sizes, int n_in,
                              void* d_out, int out_size, void* d_ws, size_t ws_size,
                              hipStream_t stream) {
    const float* x    = (const float*)d_in[0];   // [2048, 512]
    const float* emb  = (const float*)d_in[1];   // [50257, 768]
    const float* proj = (const float*)d_in[2];   // [768, 512]
    float* out = (float*)d_out;

    char* ws = (char*)d_ws;
    // static 256B-aligned workspace layout (~63.8 MB total)
    uint8_t* e8    = (uint8_t*)(ws + 0);                     // 38,731,776
    float*   inve  = (float*)(ws + 38731776);                //    201,728
    float*   enorm = (float*)(ws + 38933504);                //    201,728
    float*   h     = (float*)(ws + 39135232);                //  6,291,456
    uint8_t* h8    = (uint8_t*)(ws + 45426688);              //  1,572,864
    float*   hnorm = (float*)(ws + 46999552);                //      8,192
    float*   invh  = (float*)(ws + 47007744);                //      8,192
    int*     cnt   = (int*)(ws + 47015936);                  //      8,192
    uint2*   cand  = (uint2*)(ws + 47024128);                // 16,777,216

    hipMemsetAsync(cnt, 0, ROWS * sizeof(int), stream);

    prep_fused<<<GEMM_BLOCKS + PREP_BLOCKS, 256, 0, stream>>>(x, proj, emb, h, e8, inve, enorm);
    prep_h<<<ROWS, 192, 0, stream>>>(h, h8, hnorm, invh);
    sim_filter<<<GRID, 512, 0, stream>>>(h8, e8, invh, inve, cnt, cand);
    finalize<<<ROWS, 512, 0, stream>>>(h, emb, hnorm, enorm, cnt, cand, out);
}

// Round 13
// 375.374 us; speedup vs baseline: 1.7559x; 1.7559x over previous
//
#include <hip/hip_runtime.h>
#include <hip/hip_bf16.h>
#include <stdint.h>

// ---------------- problem constants ----------------
#define ROWS   2048        // B*T
#define DIN    512
#define DEMB   768
#define VSIZE  50257
#define NPAD   50432       // 394 * 128
#define NTILES 394
#define MTILES 16
#define GRID   (MTILES * NTILES)   // 6304 = 8 x 788
#define CAP    1024
#define THRESH 0.0985f
#define BETAC  10.0f
#define EPSC   1e-8f
#define NSTEPS 24          // 768 / BK, BK = 32
#define RANKN  48          // approx-ranked slots kept
#define EXLO   16          // ranks [EXLO, EXLO+EXN) get exact fp32 rerank
#define EXN    24
#define GEMM_BLOCKS 384    // 32 x 12
#define PREP_BLOCKS 2048

typedef __attribute__((ext_vector_type(8))) short s16x8;
typedef __attribute__((ext_vector_type(4))) float f32x4;

__device__ __forceinline__ ushort f2bf(float f) {
    uint32_t u = __float_as_uint(f);
    return (ushort)((u + 0x7FFFu + ((u >> 16) & 1u)) >> 16);  // RNE
}

// ---------------- kernel A+B fused: {emb->bf16 + norms} || {h = x @ proj^T} ----
__global__ __launch_bounds__(256) void prep_fused(const float* __restrict__ X,
                                                  const float* __restrict__ P,
                                                  const float* __restrict__ emb,
                                                  float* __restrict__ H,
                                                  ushort* __restrict__ ebf,
                                                  float* __restrict__ inve,
                                                  float* __restrict__ enorm) {
    __shared__ float As[64][33];
    __shared__ float Bs[64][33];
    int bid = blockIdx.x;
    int tid = threadIdx.x;

    if (bid < GEMM_BLOCKS) {
        int bm = bid & 31;             // 2048/64
        int bn = bid >> 5;             // 768/64
        int tx = tid & 15, ty = tid >> 4;
        int lr = tid >> 3;             // 0..31
        int lc = (tid & 7) * 4;        // 0..28
        float acc[4][4] = {};
        for (int k0 = 0; k0 < DIN; k0 += 32) {
            float4 a0 = *(const float4*)(X + (size_t)(bm * 64 + lr) * DIN + k0 + lc);
            float4 a1 = *(const float4*)(X + (size_t)(bm * 64 + lr + 32) * DIN + k0 + lc);
            float4 b0 = *(const float4*)(P + (size_t)(bn * 64 + lr) * DIN + k0 + lc);
            float4 b1 = *(const float4*)(P + (size_t)(bn * 64 + lr + 32) * DIN + k0 + lc);
            __syncthreads();
            As[lr][lc] = a0.x; As[lr][lc + 1] = a0.y; As[lr][lc + 2] = a0.z; As[lr][lc + 3] = a0.w;
            As[lr + 32][lc] = a1.x; As[lr + 32][lc + 1] = a1.y; As[lr + 32][lc + 2] = a1.z; As[lr + 32][lc + 3] = a1.w;
            Bs[lr][lc] = b0.x; Bs[lr][lc + 1] = b0.y; Bs[lr][lc + 2] = b0.z; Bs[lr][lc + 3] = b0.w;
            Bs[lr + 32][lc] = b1.x; Bs[lr + 32][lc + 1] = b1.y; Bs[lr + 32][lc + 2] = b1.z; Bs[lr + 32][lc + 3] = b1.w;
            __syncthreads();
#pragma unroll
            for (int k = 0; k < 32; ++k) {
                float a[4], b[4];
#pragma unroll
                for (int i = 0; i < 4; ++i) a[i] = As[ty * 4 + i][k];
#pragma unroll
                for (int j = 0; j < 4; ++j) b[j] = Bs[tx * 4 + j][k];
#pragma unroll
                for (int i = 0; i < 4; ++i)
#pragma unroll
                    for (int j = 0; j < 4; ++j) acc[i][j] += a[i] * b[j];
            }
        }
#pragma unroll
        for (int i = 0; i < 4; ++i)
#pragma unroll
            for (int j = 0; j < 4; ++j)
                H[(size_t)(bm * 64 + ty * 4 + i) * DEMB + bn * 64 + tx * 4 + j] = acc[i][j];
        return;
    }

    // embeddings: one wave per row, grid-stride; wave-synchronous (no barriers)
    int lane = tid & 63;
    int wid = (bid - GEMM_BLOCKS) * 4 + (tid >> 6);
    for (int v = wid; v < NPAD; v += PREP_BLOCKS * 4) {
        ushort* dst = ebf + (size_t)v * DEMB + lane * 4;
        if (v >= VSIZE) {
            ushort4 z; z.x = z.y = z.z = z.w = 0;
            *(ushort4*)(dst)       = z;
            *(ushort4*)(dst + 256) = z;
            *(ushort4*)(dst + 512) = z;
            if (lane == 0) { inve[v] = 0.f; enorm[v] = 1.f; }
            continue;
        }
        const float* src = emb + (size_t)v * DEMB + lane * 4;
        float4 x0 = *(const float4*)(src);
        float4 x1 = *(const float4*)(src + 256);
        float4 x2 = *(const float4*)(src + 512);
        ushort4 o0, o1, o2;
        o0.x = f2bf(x0.x); o0.y = f2bf(x0.y); o0.z = f2bf(x0.z); o0.w = f2bf(x0.w);
        o1.x = f2bf(x1.x); o1.y = f2bf(x1.y); o1.z = f2bf(x1.z); o1.w = f2bf(x1.w);
        o2.x = f2bf(x2.x); o2.y = f2bf(x2.y); o2.z = f2bf(x2.z); o2.w = f2bf(x2.w);
        *(ushort4*)(dst)       = o0;
        *(ushort4*)(dst + 256) = o1;
        *(ushort4*)(dst + 512) = o2;
        float s = x0.x*x0.x + x0.y*x0.y + x0.z*x0.z + x0.w*x0.w
                + x1.x*x1.x + x1.y*x1.y + x1.z*x1.z + x1.w*x1.w
                + x2.x*x2.x + x2.y*x2.y + x2.z*x2.z + x2.w*x2.w;
        for (int off = 32; off; off >>= 1) s += __shfl_down(s, off);
        if (lane == 0) {
            float n = sqrtf(s);
            enorm[v] = n;
            inve[v]  = 1.f / n;
        }
    }
}

// ---------------- kernel C: h_norm, 1/h_norm, h -> bf16 ----------------
__global__ void prep_h(const float* __restrict__ H, ushort* __restrict__ hbf,
                       float* __restrict__ hnorm, float* __restrict__ invh) {
    int r = blockIdx.x;          // 2048
    int t = threadIdx.x;         // 192
    float4 xv = *(const float4*)(H + (size_t)r * DEMB + t * 4);
    ushort4 o;
    o.x = f2bf(xv.x); o.y = f2bf(xv.y); o.z = f2bf(xv.z); o.w = f2bf(xv.w);
    *(ushort4*)(hbf + (size_t)r * DEMB + t * 4) = o;
    float s = xv.x * xv.x + xv.y * xv.y + xv.z * xv.z + xv.w * xv.w;
    for (int off = 32; off; off >>= 1) s += __shfl_down(s, off);
    __shared__ float wsum[3];
    int lane = t & 63, w = t >> 6;
    if (lane == 0) wsum[w] = s;
    __syncthreads();
    if (t == 0) {
        float n = sqrtf(wsum[0] + wsum[1] + wsum[2]);
        hnorm[r] = n;
        invh[r]  = 1.f / n;
    }
}

// ---------------- kernel D: bf16 MFMA sims + threshold filter ----------------
// R3's proven sync skeleton (STAGE t+1, counted vmcnt, raw s_barrier pair,
// slot-XOR swizzle via pre-swizzled global source) at 16 waves/block:
// 1024 thr, 4Mx4N waves, per-wave 32x32 (acc 2x2 = 16 regs), ONE stage load
// per thread (1024 x 16B = the full 16KB step) -> total regs ~55 <= 64 ->
// 8 waves/SIMD = 32 waves/CU (2 blocks x 16 waves, LDS 32KB).
__global__ __launch_bounds__(1024, 8) void sim_filter(const ushort* __restrict__ Abf,
                                                      const ushort* __restrict__ Bbf,
                                                      const float* __restrict__ invh,
                                                      const float* __restrict__ inve,
                                                      int* __restrict__ cnt,
                                                      uint2* __restrict__ cand) {
    __shared__ char lds[32768];      // buf[2] x (A 8KB + B 8KB)
    int bid = blockIdx.x;
    // XCD-chunked bijective swizzle (6304 = 8 x 788 exact)
    int lb = (bid & 7) * (GRID / 8) + (bid >> 3);
    int mt = lb & 15;
    int nt = lb >> 4;
    int m0 = mt * 128, n0 = nt * 128;
    int tid = threadIdx.x, lane = tid & 63, w = tid >> 6;   // w 0..15
    int wm = w >> 2, wn = w & 3;

    // ---- stage: one 16B load per thread. tid<512 -> A rows 0..127,
    // tid>=512 -> B rows 0..127. Dest linear; source col pre-swizzled.
    int st = tid & 511;
    int r0 = st >> 2;                                // 0..127
    int sg = ((st & 3) ^ ((r0 >> 1) & 3)) * 8;       // pre-swizzled source col
    const ushort* sP = ((tid < 512) ? (Abf + (size_t)(m0 + r0) * DEMB)
                                    : (Bbf + (size_t)(n0 + r0) * DEMB)) + sg;
    int dbase = ((tid < 512) ? 0 : 8192) + (w & 7) * 1024;  // wave-uniform

    // ---- LDS read byte-offsets (K-invariant, hoisted)
    int rr = lane & 15, hi = lane >> 4;
    int sw = (hi ^ ((rr >> 1) & 3)) * 16;
    int offA[2], offB[2];
#pragma unroll
    for (int f = 0; f < 2; ++f) {
        offA[f] = (wm * 32 + f * 16 + rr) * 64 + sw;
        offB[f] = 8192 + (wn * 32 + f * 16 + rr) * 64 + sw;
    }

    f32x4 acc[2][2];
#pragma unroll
    for (int i = 0; i < 2; ++i)
#pragma unroll
        for (int j = 0; j < 2; ++j) acc[i][j] = (f32x4)(0.f);

#define STAGE(DB)                                                                     \
    do {                                                                              \
        __builtin_amdgcn_global_load_lds(                                             \
            (const __attribute__((address_space(1))) void*)sP,                        \
            (__attribute__((address_space(3))) void*)((DB) + dbase), 16, 0, 0);       \
        sP += 32;                                                                     \
    } while (0)

    STAGE(lds);                       // prologue: step 0 -> buf 0

    for (int t = 0; t < NSTEPS; ++t) {
        if (t < NSTEPS - 1) {
            char* db = lds + (((t + 1) & 1) << 14);
            STAGE(db);
            asm volatile("s_waitcnt vmcnt(1)" ::: "memory");   // t landed, t+1 in flight
        } else {
            asm volatile("s_waitcnt vmcnt(0)" ::: "memory");
        }
        __builtin_amdgcn_s_barrier();        // all waves: buf[t&1] ready
        __builtin_amdgcn_sched_barrier(0);

        const char* cb = lds + ((t & 1) << 14);
        s16x8 a[2], b[2];
#pragma unroll
        for (int f = 0; f < 2; ++f) {
            a[f] = *(const s16x8*)(cb + offA[f]);
            b[f] = *(const s16x8*)(cb + offB[f]);
        }
        __builtin_amdgcn_s_setprio(1);
#pragma unroll
        for (int i = 0; i < 2; ++i)
#pragma unroll
            for (int j = 0; j < 2; ++j)
                acc[i][j] = __builtin_amdgcn_mfma_f32_16x16x32_bf16(a[i], b[j], acc[i][j], 0, 0, 0);
        __builtin_amdgcn_s_setprio(0);

        asm volatile("s_waitcnt lgkmcnt(0)" ::: "memory");     // ds_reads of buf[t&1] done
        __builtin_amdgcn_sched_barrier(0);
        __builtin_amdgcn_s_barrier();        // buf[t&1] reusable next iteration
        __builtin_amdgcn_sched_barrier(0);
    }
#undef STAGE

    // epilogue: C/D layout col=lane&15, row=(lane>>4)*4+reg
    int rbase = hi * 4;
#pragma unroll
    for (int i = 0; i < 2; ++i) {
        int mrow0 = m0 + wm * 32 + i * 16 + rbase;
#pragma unroll
        for (int j = 0; j < 2; ++j) {
            int ncol = n0 + wn * 32 + j * 16 + rr;
            float ie = inve[ncol];   // 0 on pad rows -> filtered
#pragma unroll
            for (int r = 0; r < 4; ++r) {
                int m = mrow0 + r;
                float sim = acc[i][j][r] * invh[m] * ie;
                if (sim > THRESH) {
                    int pos = atomicAdd(&cnt[m], 1);
                    if (pos < CAP) {
                        uint2 pk;
                        pk.x = __float_as_uint(sim);
                        pk.y = (uint32_t)ncol;
                        cand[(size_t)m * CAP + pos] = pk;
                    }
                }
            }
        }
    }
}

// ---------------- kernel E: selective exact rerank + softmax + output --------
// bf16-sim noise sigma ~1e-4, rank spacing ~3.5e-4 => approx ranks 0..15 are
// provably in the true top-32 and ranks >=40 provably out. Only approx ranks
// [16,40) get exact fp32 dots. Weights: approx for 0..15 (error ~1e-3 <<
// 2.16e-2 threshold), exact for the rest. Gather reads bf16 ebf.
__global__ __launch_bounds__(512) void finalize(const float* __restrict__ H,
                                                const float* __restrict__ emb,
                                                const ushort* __restrict__ ebf,
                                                const float* __restrict__ hnorm,
                                                const float* __restrict__ enorm,
                                                const int* __restrict__ cnt,
                                                const uint2* __restrict__ cand,
                                                float* __restrict__ out) {
    int row = blockIdx.x, tid = threadIdx.x;
    __shared__ float cval[CAP];
    __shared__ int   cidx[CAP];
    __shared__ float sval[RANKN];
    __shared__ int   sidx[RANKN];
    __shared__ float exv[EXN];
    __shared__ float selv[32];
    __shared__ int   seli[32];
    __shared__ float wts[32];

    int n = cnt[row]; if (n > CAP) n = CAP;
    for (int c = tid; c < n; c += 512) {
        uint2 p = cand[(size_t)row * CAP + c];
        cval[c] = __uint_as_float(p.x);
        cidx[c] = (int)p.y;
    }
    if (tid < RANKN) { sval[tid] = -1e30f; sidx[tid] = -1; }
    __syncthreads();

    // approx top-RANKN by rank counting (order-independent -> deterministic)
    for (int c = tid; c < n; c += 512) {
        float v = cval[c]; int id = cidx[c];
        int rank = 0;
        for (int j = 0; j < n; ++j) {
            float vj = cval[j];
            rank += (vj > v) || (vj == v && cidx[j] < id);
        }
        if (rank < RANKN) { sval[rank] = v; sidx[rank] = id; }
    }
    __syncthreads();

    // exact fp32 dots for approx ranks [EXLO, EXLO+EXN): np formula
    int lane = tid & 63, w = tid >> 6;       // 8 waves
    const float* hrow = H + (size_t)row * DEMB;
    float hreg[12];
#pragma unroll
    for (int q = 0; q < 12; ++q) hreg[q] = hrow[lane + 64 * q];
    float hn = hnorm[row];
#pragma unroll
    for (int rep = 0; rep < EXN / 8; ++rep) {
        int s = EXLO + w * (EXN / 8) + rep;
        int id = sidx[s];            // wave-uniform
        float sum = 0.f;
        if (id >= 0) {
            const float* er = emb + (size_t)id * DEMB;
#pragma unroll
            for (int q = 0; q < 12; ++q) sum += hreg[q] * er[lane + 64 * q];
            for (int off = 32; off; off >>= 1) sum += __shfl_down(sum, off);
        }
        if (lane == 0) exv[s - EXLO] = (id >= 0) ? sum / (hn * enorm[id] + EPSC) : -1e30f;
    }
    __syncthreads();

    // slots 0..15: definite-in (approx values as weights)
    if (tid < EXLO) { selv[tid] = sval[tid]; seli[tid] = sidx[tid]; }
    // slots 16..31: top-16 of exact among ranks [16,40), ties by lower index
    if (tid < EXN) {
        float v = exv[tid];
        int id = sidx[EXLO + tid];
        int keyme = (id >= 0) ? id : 1000000 + tid;
        int rank = 0;
        for (int j = 0; j < EXN; ++j) {
            float vj = exv[j];
            int kj = (sidx[EXLO + j] >= 0) ? sidx[EXLO + j] : 1000000 + j;
            rank += (vj > v) || (vj == v && kj < keyme);
        }
        if (rank < 32 - EXLO) { selv[EXLO + rank] = v; seli[EXLO + rank] = id; }
    }
    __syncthreads();

    if (tid == 0) {
        float mx = selv[0];      // approx rank-0 = global max (within ~1e-4)
        float s = 0.f;
        for (int r = 0; r < 32; ++r) {
            float e = (seli[r] >= 0) ? expf(BETAC * (selv[r] - mx)) : 0.f;
            wts[r] = e; s += e;
        }
        float inv = 1.f / s;
        for (int r = 0; r < 32; ++r) wts[r] *= inv;
    }
    __syncthreads();

    // output: weighted sum over bf16 embedding rows
    for (int col = tid; col < DEMB; col += 512) {
        float acc = 0.f;
        for (int r = 0; r < 32; ++r) {
            int id = seli[r];
            if (id >= 0) {
                float e = __uint_as_float((uint32_t)ebf[(size_t)id * DEMB + col] << 16);
                acc += wts[r] * e;
            }
        }
        out[(size_t)row * DEMB + col] = acc;
    }
}

// ---------------- launch ----------------
extern "C" void kernel_launch(void* const* d_in, const int* in_sizes, int n_in,
                              void* d_out, int out_size, void* d_ws, size_t ws_size,
                              hipStream_t stream) {
    const float* x    = (const float*)d_in[0];   // [2048, 512]
    const float* emb  = (const float*)d_in[1];   // [50257, 768]
    const float* proj = (const float*)d_in[2];   // [768, 512]
    float* out = (float*)d_out;

    char* ws = (char*)d_ws;
    // static 256B-aligned workspace layout (~104.1 MB total)
    ushort* ebf   = (ushort*)(ws + 0);                       // 77,463,552
    float*  inve  = (float*)(ws + 77463552);                 //    201,728
    float*  enorm = (float*)(ws + 77665280);                 //    201,728
    float*  h     = (float*)(ws + 77867008);                 //  6,291,456
    ushort* hbf   = (ushort*)(ws + 84158464);                //  3,145,728
    float*  hnorm = (float*)(ws + 87304192);                 //      8,192
    float*  invh  = (float*)(ws + 87312384);                 //      8,192
    int*    cnt   = (int*)(ws + 87320576);                   //      8,192
    uint2*  cand  = (uint2*)(ws + 87328768);                 // 16,777,216

    hipMemsetAsync(cnt, 0, ROWS * sizeof(int), stream);

    prep_fused<<<GEMM_BLOCKS + PREP_BLOCKS, 256, 0, stream>>>(x, proj, emb, h, ebf, inve, enorm);
    prep_h<<<ROWS, 192, 0, stream>>>(h, hbf, hnorm, invh);
    sim_filter<<<GRID, 1024, 0, stream>>>(hbf, ebf, invh, inve, cnt, cand);
    finalize<<<ROWS, 512, 0, stream>>>(h, emb, ebf, hnorm, enorm, cnt, cand, out);
}

// Round 14
// 371.290 us; speedup vs baseline: 1.7752x; 1.0110x over previous
//
#include <hip/hip_runtime.h>
#include <hip/hip_bf16.h>
#include <stdint.h>

// ---------------- problem constants ----------------
#define ROWS   2048        // B*T
#define DIN    512
#define DEMB   768
#define VSIZE  50257
#define NPAD   50432       // 394 * 128
#define NTILES 394
#define MTILES 16
#define GRID   (MTILES * NTILES)   // 6304 = 8 x 788
#define CAP    1024
#define THRESH 0.0985f
#define BETAC  10.0f
#define EPSC   1e-8f
#define NSTEPS 24          // 768 / BK, BK = 32
#define RANKN  48          // approx-ranked slots kept
#define EXLO   16          // ranks [EXLO, EXLO+EXN) get exact fp32 rerank
#define EXN    24
#define GEMM_BLOCKS 384    // 32 x 12
#define PREP_BLOCKS 2048

typedef __attribute__((ext_vector_type(8))) short s16x8;
typedef __attribute__((ext_vector_type(4))) float f32x4;

__device__ __forceinline__ ushort f2bf(float f) {
    uint32_t u = __float_as_uint(f);
    return (ushort)((u + 0x7FFFu + ((u >> 16) & 1u)) >> 16);  // RNE
}

// ---------------- kernel A+B+C fused ----------------
// blocks [0,384): fp32 NT GEMM h = x @ proj^T; epilogue also writes hbf (bf16)
//   and accumulates sumsq[row] (16-lane shfl reduce + 1 atomicAdd/row-segment).
// blocks [384,...): emb -> bf16 + e_norm, wave-per-row grid-stride (no barriers).
__global__ __launch_bounds__(256) void prep_fused(const float* __restrict__ X,
                                                  const float* __restrict__ P,
                                                  const float* __restrict__ emb,
                                                  float* __restrict__ H,
                                                  ushort* __restrict__ hbf,
                                                  float* __restrict__ sumsq,
                                                  ushort* __restrict__ ebf,
                                                  float* __restrict__ inve,
                                                  float* __restrict__ enorm) {
    __shared__ float As[64][33];
    __shared__ float Bs[64][33];
    int bid = blockIdx.x;
    int tid = threadIdx.x;

    if (bid < GEMM_BLOCKS) {
        int bm = bid & 31;             // 2048/64
        int bn = bid >> 5;             // 768/64
        int tx = tid & 15, ty = tid >> 4;
        int lr = tid >> 3;             // 0..31
        int lc = (tid & 7) * 4;        // 0..28
        float acc[4][4] = {};
        for (int k0 = 0; k0 < DIN; k0 += 32) {
            float4 a0 = *(const float4*)(X + (size_t)(bm * 64 + lr) * DIN + k0 + lc);
            float4 a1 = *(const float4*)(X + (size_t)(bm * 64 + lr + 32) * DIN + k0 + lc);
            float4 b0 = *(const float4*)(P + (size_t)(bn * 64 + lr) * DIN + k0 + lc);
            float4 b1 = *(const float4*)(P + (size_t)(bn * 64 + lr + 32) * DIN + k0 + lc);
            __syncthreads();
            As[lr][lc] = a0.x; As[lr][lc + 1] = a0.y; As[lr][lc + 2] = a0.z; As[lr][lc + 3] = a0.w;
            As[lr + 32][lc] = a1.x; As[lr + 32][lc + 1] = a1.y; As[lr + 32][lc + 2] = a1.z; As[lr + 32][lc + 3] = a1.w;
            Bs[lr][lc] = b0.x; Bs[lr][lc + 1] = b0.y; Bs[lr][lc + 2] = b0.z; Bs[lr][lc + 3] = b0.w;
            Bs[lr + 32][lc] = b1.x; Bs[lr + 32][lc + 1] = b1.y; Bs[lr + 32][lc + 2] = b1.z; Bs[lr + 32][lc + 3] = b1.w;
            __syncthreads();
#pragma unroll
            for (int k = 0; k < 32; ++k) {
                float a[4], b[4];
#pragma unroll
                for (int i = 0; i < 4; ++i) a[i] = As[ty * 4 + i][k];
#pragma unroll
                for (int j = 0; j < 4; ++j) b[j] = Bs[tx * 4 + j][k];
#pragma unroll
                for (int i = 0; i < 4; ++i)
#pragma unroll
                    for (int j = 0; j < 4; ++j) acc[i][j] += a[i] * b[j];
            }
        }
#pragma unroll
        for (int i = 0; i < 4; ++i) {
            int row = bm * 64 + ty * 4 + i;
            int col = bn * 64 + tx * 4;
#pragma unroll
            for (int j = 0; j < 4; ++j)
                H[(size_t)row * DEMB + col + j] = acc[i][j];
            ushort4 o;
            o.x = f2bf(acc[i][0]); o.y = f2bf(acc[i][1]);
            o.z = f2bf(acc[i][2]); o.w = f2bf(acc[i][3]);
            *(ushort4*)(hbf + (size_t)row * DEMB + col) = o;
            float s = acc[i][0]*acc[i][0] + acc[i][1]*acc[i][1]
                    + acc[i][2]*acc[i][2] + acc[i][3]*acc[i][3];
            s += __shfl_xor(s, 1); s += __shfl_xor(s, 2);
            s += __shfl_xor(s, 4); s += __shfl_xor(s, 8);   // 16-lane row group
            if (tx == 0) atomicAdd(&sumsq[row], s);
        }
        return;
    }

    // embeddings: one wave per row, grid-stride; wave-synchronous (no barriers)
    int lane = tid & 63;
    int wid = (bid - GEMM_BLOCKS) * 4 + (tid >> 6);
    for (int v = wid; v < NPAD; v += PREP_BLOCKS * 4) {
        ushort* dst = ebf + (size_t)v * DEMB + lane * 4;
        if (v >= VSIZE) {
            ushort4 z; z.x = z.y = z.z = z.w = 0;
            *(ushort4*)(dst)       = z;
            *(ushort4*)(dst + 256) = z;
            *(ushort4*)(dst + 512) = z;
            if (lane == 0) { inve[v] = 0.f; enorm[v] = 1.f; }
            continue;
        }
        const float* src = emb + (size_t)v * DEMB + lane * 4;
        float4 x0 = *(const float4*)(src);
        float4 x1 = *(const float4*)(src + 256);
        float4 x2 = *(const float4*)(src + 512);
        ushort4 o0, o1, o2;
        o0.x = f2bf(x0.x); o0.y = f2bf(x0.y); o0.z = f2bf(x0.z); o0.w = f2bf(x0.w);
        o1.x = f2bf(x1.x); o1.y = f2bf(x1.y); o1.z = f2bf(x1.z); o1.w = f2bf(x1.w);
        o2.x = f2bf(x2.x); o2.y = f2bf(x2.y); o2.z = f2bf(x2.z); o2.w = f2bf(x2.w);
        *(ushort4*)(dst)       = o0;
        *(ushort4*)(dst + 256) = o1;
        *(ushort4*)(dst + 512) = o2;
        float s = x0.x*x0.x + x0.y*x0.y + x0.z*x0.z + x0.w*x0.w
                + x1.x*x1.x + x1.y*x1.y + x1.z*x1.z + x1.w*x1.w
                + x2.x*x2.x + x2.y*x2.y + x2.z*x2.z + x2.w*x2.w;
        for (int off = 32; off; off >>= 1) s += __shfl_down(s, off);
        if (lane == 0) {
            float n = sqrtf(s);
            enorm[v] = n;
            inve[v]  = 1.f / n;
        }
    }
}

// ---------------- kernel D: bf16 MFMA sims + threshold filter ----------------
// R13 config (best measured: 222us, VGPR 24, Occ 76%): 1024 thr / 16 waves
// (4Mx4N), per-wave 32x32 (acc 2x2), ONE stage load per thread, R3 sync
// skeleton (STAGE t+1, vmcnt(1), raw s_barrier pair), slot-XOR swizzle via
// pre-swizzled global source. Epilogue now computes 1/h_norm = rsqrtf(sumsq).
__global__ __launch_bounds__(1024, 8) void sim_filter(const ushort* __restrict__ Abf,
                                                      const ushort* __restrict__ Bbf,
                                                      const float* __restrict__ sumsq,
                                                      const float* __restrict__ inve,
                                                      int* __restrict__ cnt,
                                                      uint2* __restrict__ cand) {
    __shared__ char lds[32768];      // buf[2] x (A 8KB + B 8KB)
    int bid = blockIdx.x;
    // XCD-chunked bijective swizzle (6304 = 8 x 788 exact)
    int lb = (bid & 7) * (GRID / 8) + (bid >> 3);
    int mt = lb & 15;
    int nt = lb >> 4;
    int m0 = mt * 128, n0 = nt * 128;
    int tid = threadIdx.x, lane = tid & 63, w = tid >> 6;   // w 0..15
    int wm = w >> 2, wn = w & 3;

    // ---- stage: one 16B load per thread. tid<512 -> A rows, tid>=512 -> B rows.
    int st = tid & 511;
    int r0 = st >> 2;                                // 0..127
    int sg = ((st & 3) ^ ((r0 >> 1) & 3)) * 8;       // pre-swizzled source col
    const ushort* sP = ((tid < 512) ? (Abf + (size_t)(m0 + r0) * DEMB)
                                    : (Bbf + (size_t)(n0 + r0) * DEMB)) + sg;
    int dbase = ((tid < 512) ? 0 : 8192) + (w & 7) * 1024;  // wave-uniform

    // ---- LDS read byte-offsets (K-invariant, hoisted)
    int rr = lane & 15, hi = lane >> 4;
    int sw = (hi ^ ((rr >> 1) & 3)) * 16;
    int offA[2], offB[2];
#pragma unroll
    for (int f = 0; f < 2; ++f) {
        offA[f] = (wm * 32 + f * 16 + rr) * 64 + sw;
        offB[f] = 8192 + (wn * 32 + f * 16 + rr) * 64 + sw;
    }

    f32x4 acc[2][2];
#pragma unroll
    for (int i = 0; i < 2; ++i)
#pragma unroll
        for (int j = 0; j < 2; ++j) acc[i][j] = (f32x4)(0.f);

#define STAGE(DB)                                                                     \
    do {                                                                              \
        __builtin_amdgcn_global_load_lds(                                             \
            (const __attribute__((address_space(1))) void*)sP,                        \
            (__attribute__((address_space(3))) void*)((DB) + dbase), 16, 0, 0);       \
        sP += 32;                                                                     \
    } while (0)

    STAGE(lds);                       // prologue: step 0 -> buf 0

    for (int t = 0; t < NSTEPS; ++t) {
        if (t < NSTEPS - 1) {
            char* db = lds + (((t + 1) & 1) << 14);
            STAGE(db);
            asm volatile("s_waitcnt vmcnt(1)" ::: "memory");   // t landed, t+1 in flight
        } else {
            asm volatile("s_waitcnt vmcnt(0)" ::: "memory");
        }
        __builtin_amdgcn_s_barrier();        // all waves: buf[t&1] ready
        __builtin_amdgcn_sched_barrier(0);

        const char* cb = lds + ((t & 1) << 14);
        s16x8 a[2], b[2];
#pragma unroll
        for (int f = 0; f < 2; ++f) {
            a[f] = *(const s16x8*)(cb + offA[f]);
            b[f] = *(const s16x8*)(cb + offB[f]);
        }
        __builtin_amdgcn_s_setprio(1);
#pragma unroll
        for (int i = 0; i < 2; ++i)
#pragma unroll
            for (int j = 0; j < 2; ++j)
                acc[i][j] = __builtin_amdgcn_mfma_f32_16x16x32_bf16(a[i], b[j], acc[i][j], 0, 0, 0);
        __builtin_amdgcn_s_setprio(0);

        asm volatile("s_waitcnt lgkmcnt(0)" ::: "memory");     // ds_reads of buf[t&1] done
        __builtin_amdgcn_sched_barrier(0);
        __builtin_amdgcn_s_barrier();        // buf[t&1] reusable next iteration
        __builtin_amdgcn_sched_barrier(0);
    }
#undef STAGE

    // epilogue: C/D layout col=lane&15, row=(lane>>4)*4+reg
    int rbase = hi * 4;
#pragma unroll
    for (int i = 0; i < 2; ++i) {
        int mrow0 = m0 + wm * 32 + i * 16 + rbase;
#pragma unroll
        for (int j = 0; j < 2; ++j) {
            int ncol = n0 + wn * 32 + j * 16 + rr;
            float ie = inve[ncol];   // 0 on pad rows -> filtered
#pragma unroll
            for (int r = 0; r < 4; ++r) {
                int m = mrow0 + r;
                float sim = acc[i][j][r] * rsqrtf(sumsq[m]) * ie;
                if (sim > THRESH) {
                    int pos = atomicAdd(&cnt[m], 1);
                    if (pos < CAP) {
                        uint2 pk;
                        pk.x = __float_as_uint(sim);
                        pk.y = (uint32_t)ncol;
                        cand[(size_t)m * CAP + pos] = pk;
                    }
                }
            }
        }
    }
}

// ---------------- kernel E: selective exact rerank + softmax + output --------
// Approx ranks 0..15 provably in true top-32; ranks >=40 provably out; exact
// fp32 dots only for ranks [16,40). Gather: slots >=16 read emb fp32 (rows
// L1/L2-hot from this block's own rerank reads); slots <16 read bf16 ebf.
__global__ __launch_bounds__(512) void finalize(const float* __restrict__ H,
                                                const float* __restrict__ emb,
                                                const ushort* __restrict__ ebf,
                                                const float* __restrict__ sumsq,
                                                const float* __restrict__ enorm,
                                                const int* __restrict__ cnt,
                                                const uint2* __restrict__ cand,
                                                float* __restrict__ out) {
    int row = blockIdx.x, tid = threadIdx.x;
    __shared__ float cval[CAP];
    __shared__ int   cidx[CAP];
    __shared__ float sval[RANKN];
    __shared__ int   sidx[RANKN];
    __shared__ float exv[EXN];
    __shared__ float selv[32];
    __shared__ int   seli[32];
    __shared__ float wts[32];

    int n = cnt[row]; if (n > CAP) n = CAP;
    for (int c = tid; c < n; c += 512) {
        uint2 p = cand[(size_t)row * CAP + c];
        cval[c] = __uint_as_float(p.x);
        cidx[c] = (int)p.y;
    }
    if (tid < RANKN) { sval[tid] = -1e30f; sidx[tid] = -1; }
    __syncthreads();

    // approx top-RANKN by rank counting (order-independent -> deterministic)
    for (int c = tid; c < n; c += 512) {
        float v = cval[c]; int id = cidx[c];
        int rank = 0;
        for (int j = 0; j < n; ++j) {
            float vj = cval[j];
            rank += (vj > v) || (vj == v && cidx[j] < id);
        }
        if (rank < RANKN) { sval[rank] = v; sidx[rank] = id; }
    }
    __syncthreads();

    // exact fp32 dots for approx ranks [EXLO, EXLO+EXN): np formula
    int lane = tid & 63, w = tid >> 6;       // 8 waves
    const float* hrow = H + (size_t)row * DEMB;
    float hreg[12];
#pragma unroll
    for (int q = 0; q < 12; ++q) hreg[q] = hrow[lane + 64 * q];
    float hn = sqrtf(sumsq[row]);
#pragma unroll
    for (int rep = 0; rep < EXN / 8; ++rep) {
        int s = EXLO + w * (EXN / 8) + rep;
        int id = sidx[s];            // wave-uniform
        float sum = 0.f;
        if (id >= 0) {
            const float* er = emb + (size_t)id * DEMB;
#pragma unroll
            for (int q = 0; q < 12; ++q) sum += hreg[q] * er[lane + 64 * q];
            for (int off = 32; off; off >>= 1) sum += __shfl_down(sum, off);
        }
        if (lane == 0) exv[s - EXLO] = (id >= 0) ? sum / (hn * enorm[id] + EPSC) : -1e30f;
    }
    __syncthreads();

    // slots 0..15: definite-in (approx values as weights)
    if (tid < EXLO) { selv[tid] = sval[tid]; seli[tid] = sidx[tid]; }
    // slots 16..31: top-16 of exact among ranks [16,40), ties by lower index
    if (tid < EXN) {
        float v = exv[tid];
        int id = sidx[EXLO + tid];
        int keyme = (id >= 0) ? id : 1000000 + tid;
        int rank = 0;
        for (int j = 0; j < EXN; ++j) {
            float vj = exv[j];
            int kj = (sidx[EXLO + j] >= 0) ? sidx[EXLO + j] : 1000000 + j;
            rank += (vj > v) || (vj == v && kj < keyme);
        }
        if (rank < 32 - EXLO) { selv[EXLO + rank] = v; seli[EXLO + rank] = id; }
    }
    __syncthreads();

    if (tid == 0) {
        float mx = selv[0];      // approx rank-0 = global max (within ~1e-4)
        float s = 0.f;
        for (int r = 0; r < 32; ++r) {
            float e = (seli[r] >= 0) ? expf(BETAC * (selv[r] - mx)) : 0.f;
            wts[r] = e; s += e;
        }
        float inv = 1.f / s;
        for (int r = 0; r < 32; ++r) wts[r] *= inv;
    }
    __syncthreads();

    // output: weighted sum; r<16 from bf16 ebf (cold), r>=16 from fp32 emb (hot)
    for (int col = tid; col < DEMB; col += 512) {
        float acc = 0.f;
#pragma unroll
        for (int r = 0; r < EXLO; ++r) {
            int id = seli[r];
            if (id >= 0) {
                float e = __uint_as_float((uint32_t)ebf[(size_t)id * DEMB + col] << 16);
                acc += wts[r] * e;
            }
        }
#pragma unroll
        for (int r = EXLO; r < 32; ++r) {
            int id = seli[r];
            if (id >= 0) acc += wts[r] * emb[(size_t)id * DEMB + col];
        }
        out[(size_t)row * DEMB + col] = acc;
    }
}

// ---------------- launch ----------------
extern "C" void kernel_launch(void* const* d_in, const int* in_sizes, int n_in,
                              void* d_out, int out_size, void* d_ws, size_t ws_size,
                              hipStream_t stream) {
    const float* x    = (const float*)d_in[0];   // [2048, 512]
    const float* emb  = (const float*)d_in[1];   // [50257, 768]
    const float* proj = (const float*)d_in[2];   // [768, 512]
    float* out = (float*)d_out;

    char* ws = (char*)d_ws;
    // static 256B-aligned workspace layout (~104.1 MB total)
    ushort* ebf   = (ushort*)(ws + 0);                       // 77,463,552
    float*  inve  = (float*)(ws + 77463552);                 //    201,728
    float*  enorm = (float*)(ws + 77665280);                 //    201,728
    float*  h     = (float*)(ws + 77867008);                 //  6,291,456
    ushort* hbf   = (ushort*)(ws + 84158464);                //  3,145,728
    int*    cnt   = (int*)(ws + 87304192);                   //      8,192
    float*  sumsq = (float*)(ws + 87312384);                 //      8,192
    uint2*  cand  = (uint2*)(ws + 87320576);                 // 16,777,216

    hipMemsetAsync(cnt, 0, 16384, stream);   // cnt + sumsq (contiguous)

    prep_fused<<<GEMM_BLOCKS + PREP_BLOCKS, 256, 0, stream>>>(x, proj, emb, h, hbf, sumsq,
                                                              ebf, inve, enorm);
    sim_filter<<<GRID, 1024, 0, stream>>>(hbf, ebf, sumsq, inve, cnt, cand);
    finalize<<<ROWS, 512, 0, stream>>>(h, emb, ebf, sumsq, enorm, cnt, cand, out);
}